// Round 8
// baseline (220.204 us; speedup 1.0000x reference)
//
#include <hip/hip_runtime.h>
#include <hip/hip_bf16.h>

#define NH 16
#define DK 64
#define DM 1024
#define BB 2
#define SS 2048
#define BS (BB*SS)   // 4096 rows of x

typedef __attribute__((ext_vector_type(8))) short bf16x8;
typedef __attribute__((ext_vector_type(4))) short short4v;
typedef __attribute__((ext_vector_type(4))) float f32x4;

#define MFMA16 __builtin_amdgcn_mfma_f32_16x16x32_bf16

// native 2^x (log2e folded into Q scale upstream)
#if __has_builtin(__builtin_amdgcn_exp2f)
#define EXP2(x) __builtin_amdgcn_exp2f(x)
#else
#define EXP2(x) __expf((x) * 0.6931471805599453f)
#endif

static __device__ __forceinline__ float bf2f(short s) {
  union { unsigned u; float f; } v;
  v.u = ((unsigned)(unsigned short)s) << 16;
  return v.f;
}
static __device__ __forceinline__ short f2bf(float f) {
  union { float f; unsigned u; } v; v.f = f;
  unsigned r = (v.u + 0x7fffu + ((v.u >> 16) & 1u)) >> 16;  // RTNE
  return (short)r;
}
// packed RTNE f32x2 -> bf16x2 (v_cvt_pk_bf16_f32 on gfx950)
static __device__ __forceinline__ unsigned pkbf(float a, float b) {
  __hip_bfloat162 h = __float22bfloat162_rn(make_float2(a, b));
  union { __hip_bfloat162 h; unsigned u; } c; c.h = h; return c.u;
}

// Swizzled LDS tile: rows of C16*16 bytes, 16B chunk index XORed with row.
template<int C16>
static __device__ __forceinline__ int soff(int row, int chunk) {
  return row*(C16*8) + ((chunk ^ (row & (C16-1))) << 3);
}

// Async global->LDS staging, 16B/lane, swizzle folded into the global address.
template<int C16, int R>
static __device__ __forceinline__ void stage(const short* __restrict__ g, int gstride,
                                             short* l, int wave, int lane) {
  const int rloc = lane / C16;
  const int c    = lane % C16;
#pragma unroll
  for (int rr = 0; rr < R; rr += 4*(64/C16)) {
    int rbase = rr + wave*(64/C16);          // wave-uniform
    int row   = rbase + rloc;
    int cg    = c ^ (row & (C16-1));
    __builtin_amdgcn_global_load_lds(
        (const __attribute__((address_space(1))) void*)(g + (size_t)row*gstride + cg*8),
        (__attribute__((address_space(3))) void*)(l + rbase*(C16*8)),
        16, 0, 0);
  }
}

// t-permutation: bijective bit shuffle so QK C-frag tile-pairs form K=32 A-frags.
// perm(rho): bits [6,5,4,3,2,1,0] <- [r6,r5,r3,r2,r4,r1,r0]
static __device__ __forceinline__ int permK(int r) {
  return ((r >> 5) << 5) | ((((r >> 2) & 3)) << 3) | (((r >> 4) & 1) << 2) | (r & 3);
}
// Like stage<8,R> but LDS row rho holds global row permK(rho).
template<int R>
static __device__ __forceinline__ void stageP(const short* __restrict__ g, int gstride,
                                              short* l, int wave, int lane) {
  const int rloc = lane >> 3;
  const int c    = lane & 7;
#pragma unroll
  for (int rr = 0; rr < R; rr += 32) {
    int rbase = rr + wave*8;                 // wave-uniform
    int row   = rbase + rloc;
    int cg    = c ^ (row & 7);
    __builtin_amdgcn_global_load_lds(
        (const __attribute__((address_space(1))) void*)(g + (size_t)permK(row)*gstride + cg*8),
        (__attribute__((address_space(3))) void*)(l + rbase*64),
        16, 0, 0);
  }
}

// ---------------------------------------------------------------- convert
__global__ __launch_bounds__(256) void k_convert(
    const float* __restrict__ x,
    const float* __restrict__ Wq, const float* __restrict__ Wk,
    const float* __restrict__ Wv, const float* __restrict__ Wc,
    short* __restrict__ xb, short* __restrict__ Wt, short* __restrict__ Wct) {
  __shared__ float T[64][65];
  const int tid = threadIdx.x;
  int bx = blockIdx.x;
  const int XB = BS*DM/(256*4);                 // 4096 blocks: x -> xb
  if (bx < XB) {
    int i = (bx*256 + tid)*4;
    float4 v = *(const float4*)&x[i];
    union { unsigned u[2]; short4v s; } o;
    o.u[0] = pkbf(v.x, v.y); o.u[1] = pkbf(v.z, v.w);
    *(short4v*)&xb[i] = o.s;
    return;
  }
  bx -= XB;
  if (bx < 48*16) {                             // Wq/Wk/Wv -> Wt[th][dk][d]
    int th = bx >> 4, d0 = (bx & 15) * 64;
    int type = th >> 4, h = th & 15;
    const float* W = ((type == 0) ? Wq : (type == 1) ? Wk : Wv)
                     + (size_t)h*DM*DK + (size_t)d0*DK;
#pragma unroll
    for (int p = 0; p < 4; p++) {
      int dr = p*16 + (tid >> 4), dkc = (tid & 15) * 4;
      float4 v = *(const float4*)&W[(size_t)dr*DK + dkc];
      T[dkc+0][dr]=v.x; T[dkc+1][dr]=v.y; T[dkc+2][dr]=v.z; T[dkc+3][dr]=v.w;
    }
    __syncthreads();
#pragma unroll
    for (int e = 0; e < 2; e++) {
      int c = tid*2 + e, dk = c >> 3, dd = (c & 7) * 8;
      union { short s[8]; int4 v; } u;
#pragma unroll
      for (int j = 0; j < 8; j++) u.s[j] = f2bf(T[dk][dd+j]);
      *(int4*)&Wt[((size_t)th*DK + dk)*DM + d0 + dd] = u.v;
    }
    return;
  }
  bx -= 48*16;                                  // Wc -> Wct[n][k]
  int n0 = (bx >> 4) * 64, k0 = (bx & 15) * 64;
#pragma unroll
  for (int p = 0; p < 4; p++) {
    int kr = p*16 + (tid >> 4), nc = (tid & 15) * 4;
    float4 v = *(const float4*)&Wc[(size_t)(k0+kr)*DM + n0 + nc];
    T[nc+0][kr]=v.x; T[nc+1][kr]=v.y; T[nc+2][kr]=v.z; T[nc+3][kr]=v.w;
  }
  __syncthreads();
#pragma unroll
  for (int e = 0; e < 2; e++) {
    int c = tid*2 + e, n = c >> 3, kk = (c & 7) * 8;
    union { short s[8]; int4 v; } u;
#pragma unroll
    for (int j = 0; j < 8; j++) u.s[j] = f2bf(T[n][kk+j]);
    *(int4*)&Wct[(size_t)(n0+n)*DM + k0 + kk] = u.v;
  }
}

// ---------------------------------------------------------------- QKV GEMM
// XCD-swizzled 1-D grid; epilogue repacks C through LDS -> b128 stores.
__global__ __launch_bounds__(256) void k_qkv(
    const short* __restrict__ xb, const short* __restrict__ Wt,
    const float* __restrict__ bq, const float* __restrict__ bk,
    const float* __restrict__ bv,
    short* __restrict__ Qb, short* __restrict__ Kb, short* __restrict__ Vb) {
  __shared__ __align__(16) short smem[128*130];  // As|Bs (32KB) then Cs (33.3KB)
  short* As = smem;
  short* Bs = smem + 8192;
  const int tid = threadIdx.x, wave = tid >> 6, lane = tid & 63;
  const int l15 = lane & 15, quad = lane >> 4;
  const int id = blockIdx.x, xcd = id & 7, j = id >> 3;
  const int m0 = (xcd*4 + (j & 3)) * 128, n0 = (j >> 2) * 128;
  const int mw = (wave & 1) * 64, nw = (wave >> 1) * 64;
  f32x4 acc[4][4] = {};
  for (int k0 = 0; k0 < DM; k0 += 64) {
    stage<8,128>(xb + (size_t)m0*DM + k0, DM, As, wave, lane);
    stage<8,128>(Wt + (size_t)n0*DM + k0, DM, Bs, wave, lane);
    __syncthreads();
#pragma unroll
    for (int ks = 0; ks < 2; ks++) {
      bf16x8 a[4], b[4];
#pragma unroll
      for (int g = 0; g < 4; g++)  a[g]  = *(const bf16x8*)&As[soff<8>(mw + g*16 + l15,  ks*4 + quad)];
#pragma unroll
      for (int nf = 0; nf < 4; nf++) b[nf] = *(const bf16x8*)&Bs[soff<8>(nw + nf*16 + l15, ks*4 + quad)];
#pragma unroll
      for (int g = 0; g < 4; g++)
#pragma unroll
        for (int nf = 0; nf < 4; nf++)
          acc[g][nf] = MFMA16(a[g], b[nf], acc[g][nf], 0, 0, 0);
    }
    __syncthreads();
  }
  // bias + scale in registers, repack through LDS (stride 130: bank-clean)
  const int th = (n0 + nw) >> 6;
  const int type = th >> 4, h = th & 15;
  const float* bias = ((type == 0) ? bq : (type == 1) ? bk : bv) + h*DK;
  const float scale = (type == 0) ? 0.18033688011112042f : 1.0f;  // 1/8*log2e for Q
#pragma unroll
  for (int nf = 0; nf < 4; nf++) {
    float bval = bias[nf*16 + l15];
#pragma unroll
    for (int g = 0; g < 4; g++)
#pragma unroll
      for (int r = 0; r < 4; r++)
        smem[(mw + g*16 + quad*4 + r)*130 + nw + nf*16 + l15] =
            f2bf((acc[g][nf][r] + bval) * scale);
  }
  __syncthreads();
  const int row = tid >> 1, half = tid & 1;
  const int th2 = (n0 >> 6) + half;
  const int type2 = th2 >> 4, h2 = th2 & 15;
  short* dst = (type2 == 0) ? Qb : (type2 == 1) ? Kb : Vb;
  const int m = m0 + row, b_ = m >> 11, s = m & (SS-1);
  short* drow = dst + (size_t)((b_*NH + h2)*SS + s)*DK;
  const short* crow = smem + row*130 + half*64;
#pragma unroll
  for (int c8 = 0; c8 < 8; c8++)
    *(int4*)&drow[c8*8] = *(const int4*)&crow[c8*8];
}

// ---------------------------------------------------------------- column stats
// Q double-buffered, 1 barrier/iter, stage overlaps QK. XCD owns 4 bh.
__global__ __launch_bounds__(256) void k_stats(
    const short* __restrict__ Qb, const short* __restrict__ Kb,
    const short* __restrict__ Vb, short* __restrict__ Vt) {
  __shared__ __align__(16) short smem[3*8192];   // Ks | Qs0 | Qs1 (48 KB)
  __shared__ float red[4][64];
  __shared__ float zinv[128];
  short* Ks = smem;
  const int tid = threadIdx.x, wave = tid >> 6, lane = tid & 63;
  const int l15 = lane & 15, quad = lane >> 4;
  const int id = blockIdx.x, xcd = id & 7, j = id >> 3;
  const int bh = xcd*4 + (j & 3), t0 = (j >> 2) * 128;
  const short* Qg = Qb + (size_t)bh * SS * DK;
  const short* Kg = Kb + (size_t)bh * SS * DK;
  const int mw = (wave & 1) * 64, nw = (wave >> 1) * 64;
  stage<8,128>(Kg + (size_t)t0*DK, DK, Ks, wave, lane);
  stage<8,128>(Qg, DK, smem + 8192, wave, lane);
  __syncthreads();
  bf16x8 kf[2][4];                              // K-tile loop-invariant: hoist
#pragma unroll
  for (int ks = 0; ks < 2; ks++)
#pragma unroll
    for (int nf = 0; nf < 4; nf++)
      kf[ks][nf] = *(const bf16x8*)&Ks[soff<8>(nw + nf*16 + l15, ks*4 + quad)];
  float csum[4] = {0.f, 0.f, 0.f, 0.f};
  for (int it = 0; it < SS/128; it++) {
    if (it + 1 < SS/128)
      stage<8,128>(Qg + (size_t)(it+1)*128*DK, DK,
                   smem + 8192 + (((it+1) & 1) << 13), wave, lane);
    const short* Qs = smem + 8192 + ((it & 1) << 13);
    f32x4 acc[4][4] = {};
#pragma unroll
    for (int ks = 0; ks < 2; ks++) {
      bf16x8 a[4];
#pragma unroll
      for (int g = 0; g < 4; g++) a[g] = *(const bf16x8*)&Qs[soff<8>(mw + g*16 + l15, ks*4 + quad)];
#pragma unroll
      for (int g = 0; g < 4; g++)
#pragma unroll
        for (int nf = 0; nf < 4; nf++)
          acc[g][nf] = MFMA16(a[g], kf[ks][nf], acc[g][nf], 0, 0, 0);
    }
#pragma unroll
    for (int nf = 0; nf < 4; nf++)
#pragma unroll
      for (int g = 0; g < 4; g++)
#pragma unroll
        for (int r = 0; r < 4; r++)
          csum[nf] += EXP2(acc[g][nf][r]);
    __syncthreads();   // drains next-Q stage; Qs[cur] free for it+2
  }
#pragma unroll
  for (int nf = 0; nf < 4; nf++) {
    csum[nf] += __shfl_xor(csum[nf], 16, 64);
    csum[nf] += __shfl_xor(csum[nf], 32, 64);
  }
  if (lane < 16) {
#pragma unroll
    for (int nf = 0; nf < 4; nf++) red[wave][nf*16 + lane] = csum[nf];
  }
  __syncthreads();
  if (tid < 128) {
    int half = tid >> 6, c = tid & 63;
    zinv[tid] = 1.0f / (red[half*2][c] + red[half*2 + 1][c]);
  }
  __syncthreads();
  short* Vtile = smem + 8192;                   // 64x128 transposed tile
  const short* Vg = Vb + (size_t)bh * SS * DK;
#pragma unroll
  for (int it = 0; it < 4; it++) {
    int c = tid + it*256;
    int trow = c >> 3, c8 = (c & 7) * 8;
    union { int4 v; short s[8]; } u;
    u.v = *(const int4*)&Vg[(size_t)(t0 + trow)*DK + c8];
    float sc = zinv[trow];
#pragma unroll
    for (int jj = 0; jj < 8; jj++) {
      int dk = c8 + jj;
      Vtile[dk*128 + (((trow >> 3) ^ (dk & 15)) << 3) + (trow & 7)] = f2bf(bf2f(u.s[jj]) * sc);
    }
  }
  __syncthreads();
  short* Vtg = Vt + (size_t)bh * DK * SS;
#pragma unroll
  for (int it = 0; it < 4; it++) {
    int row = it*16 + (tid >> 4), cc = tid & 15;
    *(int4*)&Vtg[(size_t)row*SS + t0 + cc*8] = *(const int4*)&Vtile[soff<16>(row, cc)];
  }
}

// ---------------------------------------------------------------- fused exp2(QK^T) @ V'
// K staged with permK so QK C-frag tile-pairs ARE K=32 PV A-frags (no LDS
// round-trip, PV at full K=32 rate, V reads as conflict-free b128).
__global__ __launch_bounds__(256, 2) void k_attnpv(
    const short* __restrict__ Qb, const short* __restrict__ Kb,
    const short* __restrict__ Vt, short* __restrict__ catg) {
  __shared__ __align__(16) short smem[32768];   // Ks0|Ks1(=Qs)|Vs0|Vs1 (16 KB each)
  const int tid = threadIdx.x, wave = tid >> 6, lane = tid & 63;
  const int l15 = lane & 15, quad = lane >> 4;
  const int id = blockIdx.x, xcd = id & 7, jj = id >> 3;
  const int bh = xcd*4 + (jj & 3), s0 = (jj >> 2) * 128;
  const int b = bh >> 4, h = bh & 15;
  const short* Qg  = Qb + (size_t)bh * SS * DK;
  const short* Kg  = Kb + (size_t)bh * SS * DK;
  const short* Vtg = Vt + (size_t)bh * DK * SS;
  const int th_ = wave & 1, sh = wave >> 1;     // t-half / s-half of this wave
  stage<8,128>(Qg + (size_t)s0*DK, DK, smem + 8192, wave, lane);  // Qs aliases Ks1
  stageP<128>(Kg, DK, smem, wave, lane);                           // Ks0 (permuted)
  stage<16,64>(Vtg, SS, smem + 16384, wave, lane);                 // Vs0
  __syncthreads();
  bf16x8 qf[2][4];                              // loop-invariant Q fragments
#pragma unroll
  for (int ks = 0; ks < 2; ks++)
#pragma unroll
    for (int nf = 0; nf < 4; nf++)
      qf[ks][nf] = *(const bf16x8*)&smem[8192 + soff<8>(sh*64 + nf*16 + l15, ks*4 + quad)];
  __syncthreads();                              // hoists done before Ks1 staged
  f32x4 out[4][4] = {};                         // out[nf(s)][nv(dk)]
  for (int it = 0; it < SS/128; it++) {
    const short* Ks = smem + ((it & 1) << 13);
    const short* Vs = smem + 16384 + ((it & 1) << 13);
    // S^T quarter [64 t(perm)][64 s]: A = permuted K rows, B = hoisted Q frags
    f32x4 sacc[4][4] = {};
#pragma unroll
    for (int ks = 0; ks < 2; ks++) {
      bf16x8 a[4];
#pragma unroll
      for (int g = 0; g < 4; g++)
        a[g] = *(const bf16x8*)&Ks[soff<8>(th_*64 + g*16 + l15, ks*4 + quad)];
#pragma unroll
      for (int g = 0; g < 4; g++)
#pragma unroll
        for (int nf = 0; nf < 4; nf++)
          sacc[g][nf] = MFMA16(a[g], qf[ks][nf], sacc[g][nf], 0, 0, 0);
    }
    // exp2 + pack: tile-pair (2G,2G+1) C-frags = one K=32 A-frag (perm magic)
    bf16x8 pa[4][2];                            // pa[nf][G]
#pragma unroll
    for (int G = 0; G < 2; G++)
#pragma unroll
      for (int nf = 0; nf < 4; nf++) {
        union { unsigned u[4]; bf16x8 s8; } pu;
        pu.u[0] = pkbf(EXP2(sacc[2*G][nf][0]),   EXP2(sacc[2*G][nf][1]));
        pu.u[1] = pkbf(EXP2(sacc[2*G][nf][2]),   EXP2(sacc[2*G][nf][3]));
        pu.u[2] = pkbf(EXP2(sacc[2*G+1][nf][0]), EXP2(sacc[2*G+1][nf][1]));
        pu.u[3] = pkbf(EXP2(sacc[2*G+1][nf][2]), EXP2(sacc[2*G+1][nf][3]));
        pa[nf][G] = pu.s8;
      }
    if (it + 1 < SS/128) {                      // stage next K/V over PV
      stageP<128>(Kg + (size_t)(it+1)*128*DK, DK, smem + (((it+1) & 1) << 13), wave, lane);
      stage<16,64>(Vtg + (it+1)*128, SS, smem + 16384 + (((it+1) & 1) << 13), wave, lane);
    }
    // out[s][dk] += P @ V' at K=32; B-frags = b128 reads of Vs
#pragma unroll
    for (int G = 0; G < 2; G++) {
      bf16x8 vb[4];
#pragma unroll
      for (int nv = 0; nv < 4; nv++)
        vb[nv] = *(const bf16x8*)&Vs[soff<16>(nv*16 + l15, 8*th_ + 4*G + quad)];
#pragma unroll
      for (int nf = 0; nf < 4; nf++)
#pragma unroll
        for (int nv = 0; nv < 4; nv++)
          out[nf][nv] = MFMA16(pa[nf][G], vb[nv], out[nf][nv], 0, 0, 0);
    }
    __syncthreads();                            // drains stages + Ks/Vs reads
  }
  // cross-wave reduce over t-halves, then store
  float* Pf = (float*)smem;                     // [2][64][64] f32 = 32 KB
  if (th_) {
#pragma unroll
    for (int nf = 0; nf < 4; nf++)
#pragma unroll
      for (int nv = 0; nv < 4; nv++)
#pragma unroll
        for (int r = 0; r < 4; r++)
          Pf[sh*4096 + (nf*16 + quad*4 + r)*64 + nv*16 + l15] = out[nf][nv][r];
  }
  __syncthreads();
  if (!th_) {
#pragma unroll
    for (int nf = 0; nf < 4; nf++)
#pragma unroll
      for (int nv = 0; nv < 4; nv++)
#pragma unroll
        for (int r = 0; r < 4; r++) {
          float v = out[nf][nv][r] + Pf[sh*4096 + (nf*16 + quad*4 + r)*64 + nv*16 + l15];
          int s = s0 + sh*64 + nf*16 + quad*4 + r;
          catg[(size_t)(b*SS + s)*DM + h*DK + nv*16 + l15] = f2bf(v);
        }
  }
}

// ---------------------------------------------------------------- output proj
__global__ __launch_bounds__(256) void k_final(
    const short* __restrict__ catg, const short* __restrict__ Wct,
    const float* __restrict__ bc, float* __restrict__ out) {
  __shared__ __align__(16) short As[128*64];
  __shared__ __align__(16) short Bs[128*64];
  const int tid = threadIdx.x, wave = tid >> 6, lane = tid & 63;
  const int l15 = lane & 15, quad = lane >> 4;
  const int id = blockIdx.x, xcd = id & 7, j = id >> 3;
  const int m0 = (xcd*4 + (j & 3)) * 128, n0 = (j >> 2) * 128;
  const int mw = (wave & 1) * 64, nw = (wave >> 1) * 64;
  f32x4 acc[4][4] = {};
  for (int k0 = 0; k0 < DM; k0 += 64) {
    stage<8,128>(catg + (size_t)m0*DM + k0, DM, As, wave, lane);
    stage<8,128>(Wct  + (size_t)n0*DM + k0, DM, Bs, wave, lane);
    __syncthreads();
#pragma unroll
    for (int ks = 0; ks < 2; ks++) {
      bf16x8 a[4], b[4];
#pragma unroll
      for (int g = 0; g < 4; g++)  a[g]  = *(const bf16x8*)&As[soff<8>(mw + g*16 + l15,  ks*4 + quad)];
#pragma unroll
      for (int nf = 0; nf < 4; nf++) b[nf] = *(const bf16x8*)&Bs[soff<8>(nw + nf*16 + l15, ks*4 + quad)];
#pragma unroll
      for (int g = 0; g < 4; g++)
#pragma unroll
        for (int nf = 0; nf < 4; nf++)
          acc[g][nf] = MFMA16(a[g], b[nf], acc[g][nf], 0, 0, 0);
    }
    __syncthreads();
  }
#pragma unroll
  for (int nf = 0; nf < 4; nf++) {
    int n = n0 + nw + nf*16 + l15;
    float bval = bc[n];
#pragma unroll
    for (int g = 0; g < 4; g++)
#pragma unroll
      for (int r = 0; r < 4; r++) {
        int m = m0 + mw + g*16 + quad*4 + r;
        out[(size_t)m*DM + n] = acc[g][nf][r] + bval;
      }
  }
}

extern "C" void kernel_launch(void* const* d_in, const int* in_sizes, int n_in,
                              void* d_out, int out_size, void* d_ws, size_t ws_size,
                              hipStream_t stream) {
  (void)in_sizes; (void)n_in; (void)out_size; (void)ws_size;
  const float* x  = (const float*)d_in[0];
  const float* Wq = (const float*)d_in[1];
  const float* bq = (const float*)d_in[2];
  const float* Wk = (const float*)d_in[3];
  const float* bk = (const float*)d_in[4];
  const float* Wv = (const float*)d_in[5];
  const float* bv = (const float*)d_in[6];
  const float* Wc = (const float*)d_in[7];
  const float* bc = (const float*)d_in[8];
  float* out = (float*)d_out;

  char* ws = (char*)d_ws;
  size_t o = 0;
  short* xb  = (short*)(ws + o); o += (size_t)BS*DM*2;
  short* Wt  = (short*)(ws + o); o += (size_t)3*NH*DK*DM*2;
  short* Wct = (short*)(ws + o); o += (size_t)DM*DM*2;
  short* Qb  = (short*)(ws + o); o += (size_t)BB*NH*SS*DK*2;
  short* Kb  = (short*)(ws + o); o += (size_t)BB*NH*SS*DK*2;
  short* Vb  = (short*)(ws + o); o += (size_t)BB*NH*SS*DK*2;
  short* Vt  = (short*)(ws + o); o += (size_t)BB*NH*DK*SS*2;
  short* cat = (short*)(ws + o); o += (size_t)BS*DM*2;

  const int nconv = BS*DM/(256*4) + 48*16 + 256;   // 5120 blocks
  k_convert<<<dim3(nconv), 256, 0, stream>>>(x, Wq, Wk, Wv, Wc, xb, Wt, Wct);
  k_qkv   <<<dim3(768), 256, 0, stream>>>(xb, Wt, bq, bk, bv, Qb, Kb, Vb);
  k_stats <<<dim3(512), 256, 0, stream>>>(Qb, Kb, Vb, Vt);
  k_attnpv<<<dim3(512), 256, 0, stream>>>(Qb, Kb, Vt, cat);
  k_final <<<dim3(256), 256, 0, stream>>>(cat, Wct, bc, out);
}

// Round 10
// 204.955 us; speedup vs baseline: 1.0744x; 1.0744x over previous
//
#include <hip/hip_runtime.h>
#include <hip/hip_bf16.h>

#define NH 16
#define DK 64
#define DM 1024
#define BB 2
#define SS 2048
#define BS (BB*SS)   // 4096 rows of x

typedef __attribute__((ext_vector_type(8))) short bf16x8;
typedef __attribute__((ext_vector_type(4))) short short4v;
typedef __attribute__((ext_vector_type(4))) float f32x4;

#define MFMA16 __builtin_amdgcn_mfma_f32_16x16x32_bf16

// native 2^x (log2e folded into Q scale upstream)
#if __has_builtin(__builtin_amdgcn_exp2f)
#define EXP2(x) __builtin_amdgcn_exp2f(x)
#else
#define EXP2(x) __expf((x) * 0.6931471805599453f)
#endif

static __device__ __forceinline__ float bf2f(short s) {
  union { unsigned u; float f; } v;
  v.u = ((unsigned)(unsigned short)s) << 16;
  return v.f;
}
static __device__ __forceinline__ short f2bf(float f) {
  union { float f; unsigned u; } v; v.f = f;
  unsigned r = (v.u + 0x7fffu + ((v.u >> 16) & 1u)) >> 16;  // RTNE
  return (short)r;
}
// packed RTNE f32x2 -> bf16x2 (v_cvt_pk_bf16_f32 on gfx950)
static __device__ __forceinline__ unsigned pkbf(float a, float b) {
  __hip_bfloat162 h = __float22bfloat162_rn(make_float2(a, b));
  union { __hip_bfloat162 h; unsigned u; } c; c.h = h; return c.u;
}

// Swizzled LDS tile: rows of C16*16 bytes, 16B chunk index XORed with row.
template<int C16>
static __device__ __forceinline__ int soff(int row, int chunk) {
  return row*(C16*8) + ((chunk ^ (row & (C16-1))) << 3);
}

// Async global->LDS staging, 16B/lane, swizzle folded into the global address.
template<int C16, int R>
static __device__ __forceinline__ void stage(const short* __restrict__ g, int gstride,
                                             short* l, int wave, int lane) {
  const int rloc = lane / C16;
  const int c    = lane % C16;
#pragma unroll
  for (int rr = 0; rr < R; rr += 4*(64/C16)) {
    int rbase = rr + wave*(64/C16);          // wave-uniform
    int row   = rbase + rloc;
    int cg    = c ^ (row & (C16-1));
    __builtin_amdgcn_global_load_lds(
        (const __attribute__((address_space(1))) void*)(g + (size_t)row*gstride + cg*8),
        (__attribute__((address_space(3))) void*)(l + rbase*(C16*8)),
        16, 0, 0);
  }
}

// t-permutation: bijective bit shuffle so QK C-frag tile-pairs form K=32 A-frags.
// perm(rho): bits [6,5,4,3,2,1,0] <- [r6,r5,r3,r2,r4,r1,r0]
static __device__ __forceinline__ int permK(int r) {
  return ((r >> 5) << 5) | ((((r >> 2) & 3)) << 3) | (((r >> 4) & 1) << 2) | (r & 3);
}
// Like stage<8,R> but LDS row rho holds global row permK(rho).
template<int R>
static __device__ __forceinline__ void stageP(const short* __restrict__ g, int gstride,
                                              short* l, int wave, int lane) {
  const int rloc = lane >> 3;
  const int c    = lane & 7;
#pragma unroll
  for (int rr = 0; rr < R; rr += 32) {
    int rbase = rr + wave*8;                 // wave-uniform
    int row   = rbase + rloc;
    int cg    = c ^ (row & 7);
    __builtin_amdgcn_global_load_lds(
        (const __attribute__((address_space(1))) void*)(g + (size_t)permK(row)*gstride + cg*8),
        (__attribute__((address_space(3))) void*)(l + rbase*64),
        16, 0, 0);
  }
}

// ---------------------------------------------------------------- convert
__global__ __launch_bounds__(256) void k_convert(
    const float* __restrict__ x,
    const float* __restrict__ Wq, const float* __restrict__ Wk,
    const float* __restrict__ Wv, const float* __restrict__ Wc,
    short* __restrict__ xb, short* __restrict__ Wt, short* __restrict__ Wct) {
  __shared__ float T[64][65];
  const int tid = threadIdx.x;
  int bx = blockIdx.x;
  const int XB = BS*DM/(256*4);                 // 4096 blocks: x -> xb
  if (bx < XB) {
    int i = (bx*256 + tid)*4;
    float4 v = *(const float4*)&x[i];
    union { unsigned u[2]; short4v s; } o;
    o.u[0] = pkbf(v.x, v.y); o.u[1] = pkbf(v.z, v.w);
    *(short4v*)&xb[i] = o.s;
    return;
  }
  bx -= XB;
  if (bx < 48*16) {                             // Wq/Wk/Wv -> Wt[th][dk][d]
    int th = bx >> 4, d0 = (bx & 15) * 64;
    int type = th >> 4, h = th & 15;
    const float* W = ((type == 0) ? Wq : (type == 1) ? Wk : Wv)
                     + (size_t)h*DM*DK + (size_t)d0*DK;
#pragma unroll
    for (int p = 0; p < 4; p++) {
      int dr = p*16 + (tid >> 4), dkc = (tid & 15) * 4;
      float4 v = *(const float4*)&W[(size_t)dr*DK + dkc];
      T[dkc+0][dr]=v.x; T[dkc+1][dr]=v.y; T[dkc+2][dr]=v.z; T[dkc+3][dr]=v.w;
    }
    __syncthreads();
#pragma unroll
    for (int e = 0; e < 2; e++) {
      int c = tid*2 + e, dk = c >> 3, dd = (c & 7) * 8;
      union { short s[8]; int4 v; } u;
#pragma unroll
      for (int j = 0; j < 8; j++) u.s[j] = f2bf(T[dk][dd+j]);
      *(int4*)&Wt[((size_t)th*DK + dk)*DM + d0 + dd] = u.v;
    }
    return;
  }
  bx -= 48*16;                                  // Wc -> Wct[n][k]
  int n0 = (bx >> 4) * 64, k0 = (bx & 15) * 64;
#pragma unroll
  for (int p = 0; p < 4; p++) {
    int kr = p*16 + (tid >> 4), nc = (tid & 15) * 4;
    float4 v = *(const float4*)&Wc[(size_t)(k0+kr)*DM + n0 + nc];
    T[nc+0][kr]=v.x; T[nc+1][kr]=v.y; T[nc+2][kr]=v.z; T[nc+3][kr]=v.w;
  }
  __syncthreads();
#pragma unroll
  for (int e = 0; e < 2; e++) {
    int c = tid*2 + e, n = c >> 3, kk = (c & 7) * 8;
    union { short s[8]; int4 v; } u;
#pragma unroll
    for (int j = 0; j < 8; j++) u.s[j] = f2bf(T[n][kk+j]);
    *(int4*)&Wct[(size_t)(n0+n)*DM + k0 + kk] = u.v;
  }
}

// ---------------------------------------------------------------- QKV GEMM
// XCD-swizzled 1-D grid; double-buffered K-loop (1 barrier/iter).
__global__ __launch_bounds__(256) void k_qkv(
    const short* __restrict__ xb, const short* __restrict__ Wt,
    const float* __restrict__ bq, const float* __restrict__ bk,
    const float* __restrict__ bv,
    short* __restrict__ Qb, short* __restrict__ Kb, short* __restrict__ Vb) {
  __shared__ __align__(16) short smem[32768];   // As0|As1|Bs0|Bs1 (16 KB each)
  const int tid = threadIdx.x, wave = tid >> 6, lane = tid & 63;
  const int l15 = lane & 15, quad = lane >> 4;
  const int id = blockIdx.x, xcd = id & 7, j = id >> 3;
  const int m0 = (xcd*4 + (j & 3)) * 128, n0 = (j >> 2) * 128;
  const int mw = (wave & 1) * 64, nw = (wave >> 1) * 64;
  const short* Ag = xb + (size_t)m0*DM;
  const short* Bg = Wt + (size_t)n0*DM;
  stage<8,128>(Ag, DM, smem, wave, lane);
  stage<8,128>(Bg, DM, smem + 16384, wave, lane);
  __syncthreads();
  f32x4 acc[4][4] = {};
  for (int it = 0; it < DM/64; it++) {
    if (it + 1 < DM/64) {                       // stage next K-slab over compute
      stage<8,128>(Ag + (it+1)*64, DM, smem + (((it+1) & 1) << 13), wave, lane);
      stage<8,128>(Bg + (it+1)*64, DM, smem + 16384 + (((it+1) & 1) << 13), wave, lane);
    }
    const short* As = smem + ((it & 1) << 13);
    const short* Bs = smem + 16384 + ((it & 1) << 13);
#pragma unroll
    for (int ks = 0; ks < 2; ks++) {
      bf16x8 a[4], b[4];
#pragma unroll
      for (int g = 0; g < 4; g++)  a[g]  = *(const bf16x8*)&As[soff<8>(mw + g*16 + l15,  ks*4 + quad)];
#pragma unroll
      for (int nf = 0; nf < 4; nf++) b[nf] = *(const bf16x8*)&Bs[soff<8>(nw + nf*16 + l15, ks*4 + quad)];
#pragma unroll
      for (int g = 0; g < 4; g++)
#pragma unroll
        for (int nf = 0; nf < 4; nf++)
          acc[g][nf] = MFMA16(a[g], b[nf], acc[g][nf], 0, 0, 0);
    }
    __syncthreads();                            // drains next stage; bufs swap
  }
  const int th = (n0 + nw) >> 6;
  const int type = th >> 4, h = th & 15;
  short* dst = (type == 0) ? Qb : (type == 1) ? Kb : Vb;
  const float* bias = ((type == 0) ? bq : (type == 1) ? bk : bv) + h*DK;
  // Q gets 1/sqrt(dk) * log2(e) folded in (softmax via exp2)
  const float scale = (type == 0) ? 0.18033688011112042f : 1.0f;
#pragma unroll
  for (int nf = 0; nf < 4; nf++) {
    int dk = nf*16 + l15;
    float bval = bias[dk];
#pragma unroll
    for (int g = 0; g < 4; g++)
#pragma unroll
      for (int r = 0; r < 4; r++) {
        int m = m0 + mw + g*16 + quad*4 + r;
        int b_ = m >> 11, s = m & (SS-1);
        dst[(size_t)((b_*NH + h)*SS + s)*DK + dk] = f2bf((acc[g][nf][r] + bval) * scale);
      }
  }
}

// ---------------------------------------------------------------- column stats
// Q double-buffered, 1 barrier/iter, stage overlaps QK. XCD owns 4 bh.
__global__ __launch_bounds__(256) void k_stats(
    const short* __restrict__ Qb, const short* __restrict__ Kb,
    const short* __restrict__ Vb, short* __restrict__ Vt) {
  __shared__ __align__(16) short smem[3*8192];   // Ks | Qs0 | Qs1 (48 KB)
  __shared__ float red[4][64];
  __shared__ float zinv[128];
  short* Ks = smem;
  const int tid = threadIdx.x, wave = tid >> 6, lane = tid & 63;
  const int l15 = lane & 15, quad = lane >> 4;
  const int id = blockIdx.x, xcd = id & 7, j = id >> 3;
  const int bh = xcd*4 + (j & 3), t0 = (j >> 2) * 128;
  const short* Qg = Qb + (size_t)bh * SS * DK;
  const short* Kg = Kb + (size_t)bh * SS * DK;
  const int mw = (wave & 1) * 64, nw = (wave >> 1) * 64;
  stage<8,128>(Kg + (size_t)t0*DK, DK, Ks, wave, lane);
  stage<8,128>(Qg, DK, smem + 8192, wave, lane);
  __syncthreads();
  bf16x8 kf[2][4];                              // K-tile loop-invariant: hoist
#pragma unroll
  for (int ks = 0; ks < 2; ks++)
#pragma unroll
    for (int nf = 0; nf < 4; nf++)
      kf[ks][nf] = *(const bf16x8*)&Ks[soff<8>(nw + nf*16 + l15, ks*4 + quad)];
  float csum[4] = {0.f, 0.f, 0.f, 0.f};
  for (int it = 0; it < SS/128; it++) {
    if (it + 1 < SS/128)
      stage<8,128>(Qg + (size_t)(it+1)*128*DK, DK,
                   smem + 8192 + (((it+1) & 1) << 13), wave, lane);
    const short* Qs = smem + 8192 + ((it & 1) << 13);
    f32x4 acc[4][4] = {};
#pragma unroll
    for (int ks = 0; ks < 2; ks++) {
      bf16x8 a[4];
#pragma unroll
      for (int g = 0; g < 4; g++) a[g] = *(const bf16x8*)&Qs[soff<8>(mw + g*16 + l15, ks*4 + quad)];
#pragma unroll
      for (int g = 0; g < 4; g++)
#pragma unroll
        for (int nf = 0; nf < 4; nf++)
          acc[g][nf] = MFMA16(a[g], kf[ks][nf], acc[g][nf], 0, 0, 0);
    }
#pragma unroll
    for (int nf = 0; nf < 4; nf++)
#pragma unroll
      for (int g = 0; g < 4; g++)
#pragma unroll
        for (int r = 0; r < 4; r++)
          csum[nf] += EXP2(acc[g][nf][r]);
    __syncthreads();   // drains next-Q stage; Qs[cur] free for it+2
  }
#pragma unroll
  for (int nf = 0; nf < 4; nf++) {
    csum[nf] += __shfl_xor(csum[nf], 16, 64);
    csum[nf] += __shfl_xor(csum[nf], 32, 64);
  }
  if (lane < 16) {
#pragma unroll
    for (int nf = 0; nf < 4; nf++) red[wave][nf*16 + lane] = csum[nf];
  }
  __syncthreads();
  if (tid < 128) {
    int half = tid >> 6, c = tid & 63;
    zinv[tid] = 1.0f / (red[half*2][c] + red[half*2 + 1][c]);
  }
  __syncthreads();
  short* Vtile = smem + 8192;                   // 64x128 transposed tile
  const short* Vg = Vb + (size_t)bh * SS * DK;
#pragma unroll
  for (int it = 0; it < 4; it++) {
    int c = tid + it*256;
    int trow = c >> 3, c8 = (c & 7) * 8;
    union { int4 v; short s[8]; } u;
    u.v = *(const int4*)&Vg[(size_t)(t0 + trow)*DK + c8];
    float sc = zinv[trow];
#pragma unroll
    for (int jj = 0; jj < 8; jj++) {
      int dk = c8 + jj;
      Vtile[dk*128 + (((trow >> 3) ^ (dk & 15)) << 3) + (trow & 7)] = f2bf(bf2f(u.s[jj]) * sc);
    }
  }
  __syncthreads();
  short* Vtg = Vt + (size_t)bh * DK * SS;
#pragma unroll
  for (int it = 0; it < 4; it++) {
    int row = it*16 + (tid >> 4), cc = tid & 15;
    *(int4*)&Vtg[(size_t)row*SS + t0 + cc*8] = *(const int4*)&Vtile[soff<16>(row, cc)];
  }
}

// ---------------------------------------------------------------- fused exp2(QK^T) @ V'
// K staged with permK so QK C-frag tile-pairs ARE K=32 PV A-frags (no LDS
// round-trip, PV at full K=32 rate, V reads as conflict-free b128).
__global__ __launch_bounds__(256, 2) void k_attnpv(
    const short* __restrict__ Qb, const short* __restrict__ Kb,
    const short* __restrict__ Vt, short* __restrict__ catg) {
  __shared__ __align__(16) short smem[32768];   // Ks0|Ks1(=Qs)|Vs0|Vs1 (16 KB each)
  const int tid = threadIdx.x, wave = tid >> 6, lane = tid & 63;
  const int l15 = lane & 15, quad = lane >> 4;
  const int id = blockIdx.x, xcd = id & 7, jj = id >> 3;
  const int bh = xcd*4 + (jj & 3), s0 = (jj >> 2) * 128;
  const int b = bh >> 4, h = bh & 15;
  const short* Qg  = Qb + (size_t)bh * SS * DK;
  const short* Kg  = Kb + (size_t)bh * SS * DK;
  const short* Vtg = Vt + (size_t)bh * DK * SS;
  const int th_ = wave & 1, sh = wave >> 1;     // t-half / s-half of this wave
  stage<8,128>(Qg + (size_t)s0*DK, DK, smem + 8192, wave, lane);  // Qs aliases Ks1
  stageP<128>(Kg, DK, smem, wave, lane);                           // Ks0 (permuted)
  stage<16,64>(Vtg, SS, smem + 16384, wave, lane);                 // Vs0
  __syncthreads();
  bf16x8 qf[2][4];                              // loop-invariant Q fragments
#pragma unroll
  for (int ks = 0; ks < 2; ks++)
#pragma unroll
    for (int nf = 0; nf < 4; nf++)
      qf[ks][nf] = *(const bf16x8*)&smem[8192 + soff<8>(sh*64 + nf*16 + l15, ks*4 + quad)];
  __syncthreads();                              // hoists done before Ks1 staged
  f32x4 out[4][4] = {};                         // out[nf(s)][nv(dk)]
  for (int it = 0; it < SS/128; it++) {
    const short* Ks = smem + ((it & 1) << 13);
    const short* Vs = smem + 16384 + ((it & 1) << 13);
    // S^T quarter [64 t(perm)][64 s]: A = permuted K rows, B = hoisted Q frags
    f32x4 sacc[4][4] = {};
#pragma unroll
    for (int ks = 0; ks < 2; ks++) {
      bf16x8 a[4];
#pragma unroll
      for (int g = 0; g < 4; g++)
        a[g] = *(const bf16x8*)&Ks[soff<8>(th_*64 + g*16 + l15, ks*4 + quad)];
#pragma unroll
      for (int g = 0; g < 4; g++)
#pragma unroll
        for (int nf = 0; nf < 4; nf++)
          sacc[g][nf] = MFMA16(a[g], qf[ks][nf], sacc[g][nf], 0, 0, 0);
    }
    // exp2 + pack: tile-pair (2G,2G+1) C-frags = one K=32 A-frag (perm magic)
    bf16x8 pa[4][2];                            // pa[nf][G]
#pragma unroll
    for (int G = 0; G < 2; G++)
#pragma unroll
      for (int nf = 0; nf < 4; nf++) {
        union { unsigned u[4]; bf16x8 s8; } pu;
        pu.u[0] = pkbf(EXP2(sacc[2*G][nf][0]),   EXP2(sacc[2*G][nf][1]));
        pu.u[1] = pkbf(EXP2(sacc[2*G][nf][2]),   EXP2(sacc[2*G][nf][3]));
        pu.u[2] = pkbf(EXP2(sacc[2*G+1][nf][0]), EXP2(sacc[2*G+1][nf][1]));
        pu.u[3] = pkbf(EXP2(sacc[2*G+1][nf][2]), EXP2(sacc[2*G+1][nf][3]));
        pa[nf][G] = pu.s8;
      }
    if (it + 1 < SS/128) {                      // stage next K/V over PV
      stageP<128>(Kg + (size_t)(it+1)*128*DK, DK, smem + (((it+1) & 1) << 13), wave, lane);
      stage<16,64>(Vtg + (it+1)*128, SS, smem + 16384 + (((it+1) & 1) << 13), wave, lane);
    }
    // out[s][dk] += P @ V' at K=32; B-frags = b128 reads of Vs
#pragma unroll
    for (int G = 0; G < 2; G++) {
      bf16x8 vb[4];
#pragma unroll
      for (int nv = 0; nv < 4; nv++)
        vb[nv] = *(const bf16x8*)&Vs[soff<16>(nv*16 + l15, 8*th_ + 4*G + quad)];
#pragma unroll
      for (int nf = 0; nf < 4; nf++)
#pragma unroll
        for (int nv = 0; nv < 4; nv++)
          out[nf][nv] = MFMA16(pa[nf][G], vb[nv], out[nf][nv], 0, 0, 0);
    }
    __syncthreads();                            // drains stages + Ks/Vs reads
  }
  // cross-wave reduce over t-halves, then store
  float* Pf = (float*)smem;                     // [2][64][64] f32 = 32 KB
  if (th_) {
#pragma unroll
    for (int nf = 0; nf < 4; nf++)
#pragma unroll
      for (int nv = 0; nv < 4; nv++)
#pragma unroll
        for (int r = 0; r < 4; r++)
          Pf[sh*4096 + (nf*16 + quad*4 + r)*64 + nv*16 + l15] = out[nf][nv][r];
  }
  __syncthreads();
  if (!th_) {
#pragma unroll
    for (int nf = 0; nf < 4; nf++)
#pragma unroll
      for (int nv = 0; nv < 4; nv++)
#pragma unroll
        for (int r = 0; r < 4; r++) {
          float v = out[nf][nv][r] + Pf[sh*4096 + (nf*16 + quad*4 + r)*64 + nv*16 + l15];
          int s = s0 + sh*64 + nf*16 + quad*4 + r;
          catg[(size_t)(b*SS + s)*DM + h*DK + nv*16 + l15] = f2bf(v);
        }
  }
}

// ---------------------------------------------------------------- output proj
// Double-buffered K-loop (1 barrier/iter).
__global__ __launch_bounds__(256) void k_final(
    const short* __restrict__ catg, const short* __restrict__ Wct,
    const float* __restrict__ bc, float* __restrict__ out) {
  __shared__ __align__(16) short smem[32768];   // As0|As1|Bs0|Bs1 (16 KB each)
  const int tid = threadIdx.x, wave = tid >> 6, lane = tid & 63;
  const int l15 = lane & 15, quad = lane >> 4;
  const int id = blockIdx.x, xcd = id & 7, j = id >> 3;
  const int m0 = (xcd*4 + (j & 3)) * 128, n0 = (j >> 2) * 128;
  const int mw = (wave & 1) * 64, nw = (wave >> 1) * 64;
  const short* Ag = catg + (size_t)m0*DM;
  const short* Bg = Wct  + (size_t)n0*DM;
  stage<8,128>(Ag, DM, smem, wave, lane);
  stage<8,128>(Bg, DM, smem + 16384, wave, lane);
  __syncthreads();
  f32x4 acc[4][4] = {};
  for (int it = 0; it < DM/64; it++) {
    if (it + 1 < DM/64) {
      stage<8,128>(Ag + (it+1)*64, DM, smem + (((it+1) & 1) << 13), wave, lane);
      stage<8,128>(Bg + (it+1)*64, DM, smem + 16384 + (((it+1) & 1) << 13), wave, lane);
    }
    const short* As = smem + ((it & 1) << 13);
    const short* Bs = smem + 16384 + ((it & 1) << 13);
#pragma unroll
    for (int ks = 0; ks < 2; ks++) {
      bf16x8 a[4], b[4];
#pragma unroll
      for (int g = 0; g < 4; g++)  a[g]  = *(const bf16x8*)&As[soff<8>(mw + g*16 + l15,  ks*4 + quad)];
#pragma unroll
      for (int nf = 0; nf < 4; nf++) b[nf] = *(const bf16x8*)&Bs[soff<8>(nw + nf*16 + l15, ks*4 + quad)];
#pragma unroll
      for (int g = 0; g < 4; g++)
#pragma unroll
        for (int nf = 0; nf < 4; nf++)
          acc[g][nf] = MFMA16(a[g], b[nf], acc[g][nf], 0, 0, 0);
    }
    __syncthreads();
  }
#pragma unroll
  for (int nf = 0; nf < 4; nf++) {
    int n = n0 + nw + nf*16 + l15;
    float bval = bc[n];
#pragma unroll
    for (int g = 0; g < 4; g++)
#pragma unroll
      for (int r = 0; r < 4; r++) {
        int m = m0 + mw + g*16 + quad*4 + r;
        out[(size_t)m*DM + n] = acc[g][nf][r] + bval;
      }
  }
}

extern "C" void kernel_launch(void* const* d_in, const int* in_sizes, int n_in,
                              void* d_out, int out_size, void* d_ws, size_t ws_size,
                              hipStream_t stream) {
  (void)in_sizes; (void)n_in; (void)out_size; (void)ws_size;
  const float* x  = (const float*)d_in[0];
  const float* Wq = (const float*)d_in[1];
  const float* bq = (const float*)d_in[2];
  const float* Wk = (const float*)d_in[3];
  const float* bk = (const float*)d_in[4];
  const float* Wv = (const float*)d_in[5];
  const float* bv = (const float*)d_in[6];
  const float* Wc = (const float*)d_in[7];
  const float* bc = (const float*)d_in[8];
  float* out = (float*)d_out;

  char* ws = (char*)d_ws;
  size_t o = 0;
  short* xb  = (short*)(ws + o); o += (size_t)BS*DM*2;
  short* Wt  = (short*)(ws + o); o += (size_t)3*NH*DK*DM*2;
  short* Wct = (short*)(ws + o); o += (size_t)DM*DM*2;
  short* Qb  = (short*)(ws + o); o += (size_t)BB*NH*SS*DK*2;
  short* Kb  = (short*)(ws + o); o += (size_t)BB*NH*SS*DK*2;
  short* Vb  = (short*)(ws + o); o += (size_t)BB*NH*SS*DK*2;
  short* Vt  = (short*)(ws + o); o += (size_t)BB*NH*DK*SS*2;
  short* cat = (short*)(ws + o); o += (size_t)BS*DM*2;

  const int nconv = BS*DM/(256*4) + 48*16 + 256;   // 5120 blocks
  k_convert<<<dim3(nconv), 256, 0, stream>>>(x, Wq, Wk, Wv, Wc, xb, Wt, Wct);
  k_qkv   <<<dim3(768), 256, 0, stream>>>(xb, Wt, bq, bk, bv, Qb, Kb, Vb);
  k_stats <<<dim3(512), 256, 0, stream>>>(Qb, Kb, Vb, Vt);
  k_attnpv<<<dim3(512), 256, 0, stream>>>(Qb, Kb, Vt, cat);
  k_final <<<dim3(256), 256, 0, stream>>>(cat, Wct, bc, out);
}

// Round 11
// 197.635 us; speedup vs baseline: 1.1142x; 1.0370x over previous
//
#include <hip/hip_runtime.h>
#include <hip/hip_bf16.h>

#define NH 16
#define DK 64
#define DM 1024
#define BB 2
#define SS 2048
#define BS (BB*SS)   // 4096 rows of x

typedef __attribute__((ext_vector_type(8))) short bf16x8;
typedef __attribute__((ext_vector_type(4))) short short4v;
typedef __attribute__((ext_vector_type(4))) float f32x4;

#define MFMA16 __builtin_amdgcn_mfma_f32_16x16x32_bf16

// native 2^x (log2e folded into Q scale upstream)
#if __has_builtin(__builtin_amdgcn_exp2f)
#define EXP2(x) __builtin_amdgcn_exp2f(x)
#else
#define EXP2(x) __expf((x) * 0.6931471805599453f)
#endif

static __device__ __forceinline__ float bf2f(short s) {
  union { unsigned u; float f; } v;
  v.u = ((unsigned)(unsigned short)s) << 16;
  return v.f;
}
static __device__ __forceinline__ short f2bf(float f) {
  union { float f; unsigned u; } v; v.f = f;
  unsigned r = (v.u + 0x7fffu + ((v.u >> 16) & 1u)) >> 16;  // RTNE
  return (short)r;
}
// packed RTNE f32x2 -> bf16x2 (v_cvt_pk_bf16_f32 on gfx950)
static __device__ __forceinline__ unsigned pkbf(float a, float b) {
  __hip_bfloat162 h = __float22bfloat162_rn(make_float2(a, b));
  union { __hip_bfloat162 h; unsigned u; } c; c.h = h; return c.u;
}

// Swizzled LDS tile: rows of C16*16 bytes, 16B chunk index XORed with row.
template<int C16>
static __device__ __forceinline__ int soff(int row, int chunk) {
  return row*(C16*8) + ((chunk ^ (row & (C16-1))) << 3);
}

// Async global->LDS staging, 16B/lane, swizzle folded into the global address.
template<int C16, int R>
static __device__ __forceinline__ void stage(const short* __restrict__ g, int gstride,
                                             short* l, int wave, int lane) {
  const int rloc = lane / C16;
  const int c    = lane % C16;
#pragma unroll
  for (int rr = 0; rr < R; rr += 4*(64/C16)) {
    int rbase = rr + wave*(64/C16);          // wave-uniform
    int row   = rbase + rloc;
    int cg    = c ^ (row & (C16-1));
    __builtin_amdgcn_global_load_lds(
        (const __attribute__((address_space(1))) void*)(g + (size_t)row*gstride + cg*8),
        (__attribute__((address_space(3))) void*)(l + rbase*(C16*8)),
        16, 0, 0);
  }
}

// t-permutation: bijective bit shuffle so QK C-frag tile-pairs form K=32 A-frags.
// perm(rho): bits [6,5,4,3,2,1,0] <- [r6,r5,r3,r2,r4,r1,r0]
static __device__ __forceinline__ int permK(int r) {
  return ((r >> 5) << 5) | ((((r >> 2) & 3)) << 3) | (((r >> 4) & 1) << 2) | (r & 3);
}
// Like stage<8,R> but LDS row rho holds global row permK(rho).
template<int R>
static __device__ __forceinline__ void stageP(const short* __restrict__ g, int gstride,
                                              short* l, int wave, int lane) {
  const int rloc = lane >> 3;
  const int c    = lane & 7;
#pragma unroll
  for (int rr = 0; rr < R; rr += 32) {
    int rbase = rr + wave*8;                 // wave-uniform
    int row   = rbase + rloc;
    int cg    = c ^ (row & 7);
    __builtin_amdgcn_global_load_lds(
        (const __attribute__((address_space(1))) void*)(g + (size_t)permK(row)*gstride + cg*8),
        (__attribute__((address_space(3))) void*)(l + rbase*64),
        16, 0, 0);
  }
}

// ---------------------------------------------------------------- convert
__global__ __launch_bounds__(256) void k_convert(
    const float* __restrict__ x,
    const float* __restrict__ Wq, const float* __restrict__ Wk,
    const float* __restrict__ Wv, const float* __restrict__ Wc,
    short* __restrict__ xb, short* __restrict__ Wt, short* __restrict__ Wct) {
  __shared__ float T[64][65];
  const int tid = threadIdx.x;
  int bx = blockIdx.x;
  const int XB = BS*DM/(256*4);                 // 4096 blocks: x -> xb
  if (bx < XB) {
    int i = (bx*256 + tid)*4;
    float4 v = *(const float4*)&x[i];
    union { unsigned u[2]; short4v s; } o;
    o.u[0] = pkbf(v.x, v.y); o.u[1] = pkbf(v.z, v.w);
    *(short4v*)&xb[i] = o.s;
    return;
  }
  bx -= XB;
  if (bx < 48*16) {                             // Wq/Wk/Wv -> Wt[th][dk][d]
    int th = bx >> 4, d0 = (bx & 15) * 64;
    int type = th >> 4, h = th & 15;
    const float* W = ((type == 0) ? Wq : (type == 1) ? Wk : Wv)
                     + (size_t)h*DM*DK + (size_t)d0*DK;
#pragma unroll
    for (int p = 0; p < 4; p++) {
      int dr = p*16 + (tid >> 4), dkc = (tid & 15) * 4;
      float4 v = *(const float4*)&W[(size_t)dr*DK + dkc];
      T[dkc+0][dr]=v.x; T[dkc+1][dr]=v.y; T[dkc+2][dr]=v.z; T[dkc+3][dr]=v.w;
    }
    __syncthreads();
#pragma unroll
    for (int e = 0; e < 2; e++) {
      int c = tid*2 + e, dk = c >> 3, dd = (c & 7) * 8;
      union { short s[8]; int4 v; } u;
#pragma unroll
      for (int j = 0; j < 8; j++) u.s[j] = f2bf(T[dk][dd+j]);
      *(int4*)&Wt[((size_t)th*DK + dk)*DM + d0 + dd] = u.v;
    }
    return;
  }
  bx -= 48*16;                                  // Wc -> Wct[n][k]
  int n0 = (bx >> 4) * 64, k0 = (bx & 15) * 64;
#pragma unroll
  for (int p = 0; p < 4; p++) {
    int kr = p*16 + (tid >> 4), nc = (tid & 15) * 4;
    float4 v = *(const float4*)&Wc[(size_t)(k0+kr)*DM + n0 + nc];
    T[nc+0][kr]=v.x; T[nc+1][kr]=v.y; T[nc+2][kr]=v.z; T[nc+3][kr]=v.w;
  }
  __syncthreads();
#pragma unroll
  for (int e = 0; e < 2; e++) {
    int c = tid*2 + e, n = c >> 3, kk = (c & 7) * 8;
    union { short s[8]; int4 v; } u;
#pragma unroll
    for (int j = 0; j < 8; j++) u.s[j] = f2bf(T[n][kk+j]);
    *(int4*)&Wct[(size_t)(n0+n)*DM + k0 + kk] = u.v;
  }
}

// ---------------------------------------------------------------- QKV GEMM
// XCD-swizzled 1-D grid; double-buffered K-loop (1 barrier/iter).
__global__ __launch_bounds__(256) void k_qkv(
    const short* __restrict__ xb, const short* __restrict__ Wt,
    const float* __restrict__ bq, const float* __restrict__ bk,
    const float* __restrict__ bv,
    short* __restrict__ Qb, short* __restrict__ Kb, short* __restrict__ Vb) {
  __shared__ __align__(16) short smem[32768];   // As0|As1|Bs0|Bs1 (16 KB each)
  const int tid = threadIdx.x, wave = tid >> 6, lane = tid & 63;
  const int l15 = lane & 15, quad = lane >> 4;
  const int id = blockIdx.x, xcd = id & 7, j = id >> 3;
  const int m0 = (xcd*4 + (j & 3)) * 128, n0 = (j >> 2) * 128;
  const int mw = (wave & 1) * 64, nw = (wave >> 1) * 64;
  const short* Ag = xb + (size_t)m0*DM;
  const short* Bg = Wt + (size_t)n0*DM;
  stage<8,128>(Ag, DM, smem, wave, lane);
  stage<8,128>(Bg, DM, smem + 16384, wave, lane);
  __syncthreads();
  f32x4 acc[4][4] = {};
  for (int it = 0; it < DM/64; it++) {
    if (it + 1 < DM/64) {                       // stage next K-slab over compute
      stage<8,128>(Ag + (it+1)*64, DM, smem + (((it+1) & 1) << 13), wave, lane);
      stage<8,128>(Bg + (it+1)*64, DM, smem + 16384 + (((it+1) & 1) << 13), wave, lane);
    }
    const short* As = smem + ((it & 1) << 13);
    const short* Bs = smem + 16384 + ((it & 1) << 13);
#pragma unroll
    for (int ks = 0; ks < 2; ks++) {
      bf16x8 a[4], b[4];
#pragma unroll
      for (int g = 0; g < 4; g++)  a[g]  = *(const bf16x8*)&As[soff<8>(mw + g*16 + l15,  ks*4 + quad)];
#pragma unroll
      for (int nf = 0; nf < 4; nf++) b[nf] = *(const bf16x8*)&Bs[soff<8>(nw + nf*16 + l15, ks*4 + quad)];
#pragma unroll
      for (int g = 0; g < 4; g++)
#pragma unroll
        for (int nf = 0; nf < 4; nf++)
          acc[g][nf] = MFMA16(a[g], b[nf], acc[g][nf], 0, 0, 0);
    }
    __syncthreads();                            // drains next stage; bufs swap
  }
  const int th = (n0 + nw) >> 6;
  const int type = th >> 4, h = th & 15;
  short* dst = (type == 0) ? Qb : (type == 1) ? Kb : Vb;
  const float* bias = ((type == 0) ? bq : (type == 1) ? bk : bv) + h*DK;
  // Q gets 1/sqrt(dk) * log2(e) folded in (softmax via exp2)
  const float scale = (type == 0) ? 0.18033688011112042f : 1.0f;
#pragma unroll
  for (int nf = 0; nf < 4; nf++) {
    int dk = nf*16 + l15;
    float bval = bias[dk];
#pragma unroll
    for (int g = 0; g < 4; g++)
#pragma unroll
      for (int r = 0; r < 4; r++) {
        int m = m0 + mw + g*16 + quad*4 + r;
        int b_ = m >> 11, s = m & (SS-1);
        dst[(size_t)((b_*NH + h)*SS + s)*DK + dk] = f2bf((acc[g][nf][r] + bval) * scale);
      }
  }
}

// ---------------------------------------------------------------- column stats
// Q double-buffered, 1 barrier/iter, stage overlaps QK. XCD owns 4 bh.
__global__ __launch_bounds__(256) void k_stats(
    const short* __restrict__ Qb, const short* __restrict__ Kb,
    const short* __restrict__ Vb, short* __restrict__ Vt) {
  __shared__ __align__(16) short smem[3*8192];   // Ks | Qs0 | Qs1 (48 KB)
  __shared__ float red[4][64];
  __shared__ float zinv[128];
  short* Ks = smem;
  const int tid = threadIdx.x, wave = tid >> 6, lane = tid & 63;
  const int l15 = lane & 15, quad = lane >> 4;
  const int id = blockIdx.x, xcd = id & 7, j = id >> 3;
  const int bh = xcd*4 + (j & 3), t0 = (j >> 2) * 128;
  const short* Qg = Qb + (size_t)bh * SS * DK;
  const short* Kg = Kb + (size_t)bh * SS * DK;
  const int mw = (wave & 1) * 64, nw = (wave >> 1) * 64;
  stage<8,128>(Kg + (size_t)t0*DK, DK, Ks, wave, lane);
  stage<8,128>(Qg, DK, smem + 8192, wave, lane);
  __syncthreads();
  bf16x8 kf[2][4];                              // K-tile loop-invariant: hoist
#pragma unroll
  for (int ks = 0; ks < 2; ks++)
#pragma unroll
    for (int nf = 0; nf < 4; nf++)
      kf[ks][nf] = *(const bf16x8*)&Ks[soff<8>(nw + nf*16 + l15, ks*4 + quad)];
  float csum[4] = {0.f, 0.f, 0.f, 0.f};
  for (int it = 0; it < SS/128; it++) {
    if (it + 1 < SS/128)
      stage<8,128>(Qg + (size_t)(it+1)*128*DK, DK,
                   smem + 8192 + (((it+1) & 1) << 13), wave, lane);
    const short* Qs = smem + 8192 + ((it & 1) << 13);
    f32x4 acc[4][4] = {};
#pragma unroll
    for (int ks = 0; ks < 2; ks++) {
      bf16x8 a[4];
#pragma unroll
      for (int g = 0; g < 4; g++) a[g] = *(const bf16x8*)&Qs[soff<8>(mw + g*16 + l15, ks*4 + quad)];
#pragma unroll
      for (int g = 0; g < 4; g++)
#pragma unroll
        for (int nf = 0; nf < 4; nf++)
          acc[g][nf] = MFMA16(a[g], kf[ks][nf], acc[g][nf], 0, 0, 0);
    }
#pragma unroll
    for (int nf = 0; nf < 4; nf++)
#pragma unroll
      for (int g = 0; g < 4; g++)
#pragma unroll
        for (int r = 0; r < 4; r++)
          csum[nf] += EXP2(acc[g][nf][r]);
    __syncthreads();   // drains next-Q stage; Qs[cur] free for it+2
  }
#pragma unroll
  for (int nf = 0; nf < 4; nf++) {
    csum[nf] += __shfl_xor(csum[nf], 16, 64);
    csum[nf] += __shfl_xor(csum[nf], 32, 64);
  }
  if (lane < 16) {
#pragma unroll
    for (int nf = 0; nf < 4; nf++) red[wave][nf*16 + lane] = csum[nf];
  }
  __syncthreads();
  if (tid < 128) {
    int half = tid >> 6, c = tid & 63;
    zinv[tid] = 1.0f / (red[half*2][c] + red[half*2 + 1][c]);
  }
  __syncthreads();
  short* Vtile = smem + 8192;                   // 64x128 transposed tile
  const short* Vg = Vb + (size_t)bh * SS * DK;
#pragma unroll
  for (int it = 0; it < 4; it++) {
    int c = tid + it*256;
    int trow = c >> 3, c8 = (c & 7) * 8;
    union { int4 v; short s[8]; } u;
    u.v = *(const int4*)&Vg[(size_t)(t0 + trow)*DK + c8];
    float sc = zinv[trow];
#pragma unroll
    for (int jj = 0; jj < 8; jj++) {
      int dk = c8 + jj;
      Vtile[dk*128 + (((trow >> 3) ^ (dk & 15)) << 3) + (trow & 7)] = f2bf(bf2f(u.s[jj]) * sc);
    }
  }
  __syncthreads();
  short* Vtg = Vt + (size_t)bh * DK * SS;
#pragma unroll
  for (int it = 0; it < 4; it++) {
    int row = it*16 + (tid >> 4), cc = tid & 15;
    *(int4*)&Vtg[(size_t)row*SS + t0 + cc*8] = *(const int4*)&Vtile[soff<16>(row, cc)];
  }
}

// ---------------------------------------------------------------- fused exp2(QK^T) @ V'
// K staged with permK so QK C-frag tile-pairs ARE K=32 PV A-frags. Prefetch
// staging issued at LOOP TOP so it shadows the full QK+pack+PV phase.
__global__ __launch_bounds__(256, 2) void k_attnpv(
    const short* __restrict__ Qb, const short* __restrict__ Kb,
    const short* __restrict__ Vt, short* __restrict__ catg) {
  __shared__ __align__(16) short smem[32768];   // Ks0|Ks1(=Qs)|Vs0|Vs1 (16 KB each)
  const int tid = threadIdx.x, wave = tid >> 6, lane = tid & 63;
  const int l15 = lane & 15, quad = lane >> 4;
  const int id = blockIdx.x, xcd = id & 7, jj = id >> 3;
  const int bh = xcd*4 + (jj & 3), s0 = (jj >> 2) * 128;
  const int b = bh >> 4, h = bh & 15;
  const short* Qg  = Qb + (size_t)bh * SS * DK;
  const short* Kg  = Kb + (size_t)bh * SS * DK;
  const short* Vtg = Vt + (size_t)bh * DK * SS;
  const int th_ = wave & 1, sh = wave >> 1;     // t-half / s-half of this wave
  stage<8,128>(Qg + (size_t)s0*DK, DK, smem + 8192, wave, lane);  // Qs aliases Ks1
  stageP<128>(Kg, DK, smem, wave, lane);                           // Ks0 (permuted)
  stage<16,64>(Vtg, SS, smem + 16384, wave, lane);                 // Vs0
  __syncthreads();
  bf16x8 qf[2][4];                              // loop-invariant Q fragments
#pragma unroll
  for (int ks = 0; ks < 2; ks++)
#pragma unroll
    for (int nf = 0; nf < 4; nf++)
      qf[ks][nf] = *(const bf16x8*)&smem[8192 + soff<8>(sh*64 + nf*16 + l15, ks*4 + quad)];
  __syncthreads();                              // hoists done before Ks1 staged
  f32x4 out[4][4] = {};                         // out[nf(s)][nv(dk)]
  for (int it = 0; it < SS/128; it++) {
    if (it + 1 < SS/128) {                      // prefetch at TOP: full-iter shadow
      stageP<128>(Kg + (size_t)(it+1)*128*DK, DK, smem + (((it+1) & 1) << 13), wave, lane);
      stage<16,64>(Vtg + (it+1)*128, SS, smem + 16384 + (((it+1) & 1) << 13), wave, lane);
    }
    const short* Ks = smem + ((it & 1) << 13);
    const short* Vs = smem + 16384 + ((it & 1) << 13);
    // S^T quarter [64 t(perm)][64 s]: A = permuted K rows, B = hoisted Q frags
    f32x4 sacc[4][4] = {};
#pragma unroll
    for (int ks = 0; ks < 2; ks++) {
      bf16x8 a[4];
#pragma unroll
      for (int g = 0; g < 4; g++)
        a[g] = *(const bf16x8*)&Ks[soff<8>(th_*64 + g*16 + l15, ks*4 + quad)];
#pragma unroll
      for (int g = 0; g < 4; g++)
#pragma unroll
        for (int nf = 0; nf < 4; nf++)
          sacc[g][nf] = MFMA16(a[g], qf[ks][nf], sacc[g][nf], 0, 0, 0);
    }
    // exp2 + pack: tile-pair (2G,2G+1) C-frags = one K=32 A-frag (perm magic)
    bf16x8 pa[4][2];                            // pa[nf][G]
#pragma unroll
    for (int G = 0; G < 2; G++)
#pragma unroll
      for (int nf = 0; nf < 4; nf++) {
        union { unsigned u[4]; bf16x8 s8; } pu;
        pu.u[0] = pkbf(EXP2(sacc[2*G][nf][0]),   EXP2(sacc[2*G][nf][1]));
        pu.u[1] = pkbf(EXP2(sacc[2*G][nf][2]),   EXP2(sacc[2*G][nf][3]));
        pu.u[2] = pkbf(EXP2(sacc[2*G+1][nf][0]), EXP2(sacc[2*G+1][nf][1]));
        pu.u[3] = pkbf(EXP2(sacc[2*G+1][nf][2]), EXP2(sacc[2*G+1][nf][3]));
        pa[nf][G] = pu.s8;
      }
    // out[s][dk] += P @ V' at K=32; B-frags = b128 reads of Vs
#pragma unroll
    for (int G = 0; G < 2; G++) {
      bf16x8 vb[4];
#pragma unroll
      for (int nv = 0; nv < 4; nv++)
        vb[nv] = *(const bf16x8*)&Vs[soff<16>(nv*16 + l15, 8*th_ + 4*G + quad)];
#pragma unroll
      for (int nf = 0; nf < 4; nf++)
#pragma unroll
        for (int nv = 0; nv < 4; nv++)
          out[nf][nv] = MFMA16(pa[nf][G], vb[nv], out[nf][nv], 0, 0, 0);
    }
    __syncthreads();                            // drains stages + Ks/Vs reads
  }
  // cross-wave reduce over t-halves, then store
  float* Pf = (float*)smem;                     // [2][64][64] f32 = 32 KB
  if (th_) {
#pragma unroll
    for (int nf = 0; nf < 4; nf++)
#pragma unroll
      for (int nv = 0; nv < 4; nv++)
#pragma unroll
        for (int r = 0; r < 4; r++)
          Pf[sh*4096 + (nf*16 + quad*4 + r)*64 + nv*16 + l15] = out[nf][nv][r];
  }
  __syncthreads();
  if (!th_) {
#pragma unroll
    for (int nf = 0; nf < 4; nf++)
#pragma unroll
      for (int nv = 0; nv < 4; nv++)
#pragma unroll
        for (int r = 0; r < 4; r++) {
          float v = out[nf][nv][r] + Pf[sh*4096 + (nf*16 + quad*4 + r)*64 + nv*16 + l15];
          int s = s0 + sh*64 + nf*16 + quad*4 + r;
          catg[(size_t)(b*SS + s)*DM + h*DK + nv*16 + l15] = f2bf(v);
        }
  }
}

// ---------------------------------------------------------------- output proj
// 128x64 tile, 48 KB LDS -> 3 blocks/CU; double-buffered K-loop.
__global__ __launch_bounds__(256) void k_final(
    const short* __restrict__ catg, const short* __restrict__ Wct,
    const float* __restrict__ bc, float* __restrict__ out) {
  __shared__ __align__(16) short smem[24576];   // As0|As1 (8K shorts ea) | Bs0|Bs1 (4K ea)
  const int tid = threadIdx.x, wave = tid >> 6, lane = tid & 63;
  const int l15 = lane & 15, quad = lane >> 4;
  const int id = blockIdx.x, xcd = id & 7, j = id >> 3;
  const int m0 = (xcd*4 + (j & 3)) * 128, n0 = (j >> 2) * 64;
  const int mw = (wave & 1) * 64, nw = (wave >> 1) * 32;
  const short* Ag = catg + (size_t)m0*DM;
  const short* Bg = Wct  + (size_t)n0*DM;
  stage<8,128>(Ag, DM, smem, wave, lane);
  stage<8,64>(Bg, DM, smem + 16384, wave, lane);
  __syncthreads();
  f32x4 acc[4][2] = {};
  for (int it = 0; it < DM/64; it++) {
    if (it + 1 < DM/64) {
      stage<8,128>(Ag + (it+1)*64, DM, smem + (((it+1) & 1) << 13), wave, lane);
      stage<8,64>(Bg + (it+1)*64, DM, smem + 16384 + (((it+1) & 1) << 12), wave, lane);
    }
    const short* As = smem + ((it & 1) << 13);
    const short* Bs = smem + 16384 + ((it & 1) << 12);
#pragma unroll
    for (int ks = 0; ks < 2; ks++) {
      bf16x8 a[4], b[2];
#pragma unroll
      for (int g = 0; g < 4; g++)  a[g]  = *(const bf16x8*)&As[soff<8>(mw + g*16 + l15,  ks*4 + quad)];
#pragma unroll
      for (int nf = 0; nf < 2; nf++) b[nf] = *(const bf16x8*)&Bs[soff<8>(nw + nf*16 + l15, ks*4 + quad)];
#pragma unroll
      for (int g = 0; g < 4; g++)
#pragma unroll
        for (int nf = 0; nf < 2; nf++)
          acc[g][nf] = MFMA16(a[g], b[nf], acc[g][nf], 0, 0, 0);
    }
    __syncthreads();
  }
#pragma unroll
  for (int nf = 0; nf < 2; nf++) {
    int n = n0 + nw + nf*16 + l15;
    float bval = bc[n];
#pragma unroll
    for (int g = 0; g < 4; g++)
#pragma unroll
      for (int r = 0; r < 4; r++) {
        int m = m0 + mw + g*16 + quad*4 + r;
        out[(size_t)m*DM + n] = acc[g][nf][r] + bval;
      }
  }
}

extern "C" void kernel_launch(void* const* d_in, const int* in_sizes, int n_in,
                              void* d_out, int out_size, void* d_ws, size_t ws_size,
                              hipStream_t stream) {
  (void)in_sizes; (void)n_in; (void)out_size; (void)ws_size;
  const float* x  = (const float*)d_in[0];
  const float* Wq = (const float*)d_in[1];
  const float* bq = (const float*)d_in[2];
  const float* Wk = (const float*)d_in[3];
  const float* bk = (const float*)d_in[4];
  const float* Wv = (const float*)d_in[5];
  const float* bv = (const float*)d_in[6];
  const float* Wc = (const float*)d_in[7];
  const float* bc = (const float*)d_in[8];
  float* out = (float*)d_out;

  char* ws = (char*)d_ws;
  size_t o = 0;
  short* xb  = (short*)(ws + o); o += (size_t)BS*DM*2;
  short* Wt  = (short*)(ws + o); o += (size_t)3*NH*DK*DM*2;
  short* Wct = (short*)(ws + o); o += (size_t)DM*DM*2;
  short* Qb  = (short*)(ws + o); o += (size_t)BB*NH*SS*DK*2;
  short* Kb  = (short*)(ws + o); o += (size_t)BB*NH*SS*DK*2;
  short* Vb  = (short*)(ws + o); o += (size_t)BB*NH*SS*DK*2;
  short* Vt  = (short*)(ws + o); o += (size_t)BB*NH*DK*SS*2;
  short* cat = (short*)(ws + o); o += (size_t)BS*DM*2;

  const int nconv = BS*DM/(256*4) + 48*16 + 256;   // 5120 blocks
  k_convert<<<dim3(nconv), 256, 0, stream>>>(x, Wq, Wk, Wv, Wc, xb, Wt, Wct);
  k_qkv   <<<dim3(768), 256, 0, stream>>>(xb, Wt, bq, bk, bv, Qb, Kb, Vb);
  k_stats <<<dim3(512), 256, 0, stream>>>(Qb, Kb, Vb, Vt);
  k_attnpv<<<dim3(512), 256, 0, stream>>>(Qb, Kb, Vt, cat);
  k_final <<<dim3(512), 256, 0, stream>>>(cat, Wct, bc, out);
}